// Round 4
// baseline (88.306 us; speedup 1.0000x reference)
//
#include <hip/hip_runtime.h>

// RSA layer, last-row-only formulation, single launch, 32 blocks x 4 units.
//
// out[u] = (sum_j e^{s[j,u]} * fs[j,u]) / (sum_j e^{s[j,u]})
//   s[j,u] = sum_k fs[j,k] * v[k,u],   v[k,u] = w_hi[k,u] + w_dot[u]*input[k]
// (proj_hj[1023,:] and b are constant in j -> cancel in the softmax over j;
//  |s| <~ 8 so e^s is fp32-safe without max subtraction.)
// fs[j,k] = state[k, j+1] for j<1023;  fs[1023,k] = input[k].
//
// Block b owns u0=4b..4b+3. Thread t owns state columns 4t..4t+3 (j=4t-1..4t+2);
// the dead j=-1 slot of thread 0 is patched with j=1023 (computed from input).
// 32 blocks (not 128) => 4x less redundant state traffic in the post-poison
// cold-cache environment; still one dispatch (beats the 2-launch j-split).

constexpr int U = 128;
constexpr int W = 1024;

__global__ __launch_bounds__(256) void rsa_last_kernel(
    const float* __restrict__ input,   // (128,)
    const float* __restrict__ state,   // (128,1024) row-major
    const float* __restrict__ w,       // (257,128) row-major
    float* __restrict__ out)           // (128,)
{
    const int u0   = blockIdx.x * 4;
    const int t    = threadIdx.x;
    const int lane = t & 63;
    const int wv   = t >> 6;

    __shared__ __align__(16) float4 v4[U];      // v[k][u0..u0+3]
    __shared__ float  s1023r[2][4];             // cross-wave partials for s[1023,:]
    __shared__ float4 s1023;                    // s[1023, u0..u0+3]
    __shared__ float  red[4][8];                // per-wave {num0..3, den0..3}
    __shared__ float  fin[8];

    // ---- build v4[k] = w_hi[k, u0..u0+3] + w_dot[u0..u0+3]*input[k] ----
    // also reduce s1023[m] = sum_k v[k][m] * input[k]
    const float4 wd4 = *(const float4*)&w[2 * U * U + u0];   // wave-uniform
    if (t < U) {
        const float  ik = input[t];
        const float4 wh = *(const float4*)&w[t * U + u0];
        float4 vk;
        vk.x = fmaf(wd4.x, ik, wh.x);
        vk.y = fmaf(wd4.y, ik, wh.y);
        vk.z = fmaf(wd4.z, ik, wh.z);
        vk.w = fmaf(wd4.w, ik, wh.w);
        v4[t] = vk;
        float p0 = vk.x * ik, p1 = vk.y * ik, p2 = vk.z * ik, p3 = vk.w * ik;
        #pragma unroll
        for (int o = 32; o > 0; o >>= 1) {
            p0 += __shfl_down(p0, o, 64);
            p1 += __shfl_down(p1, o, 64);
            p2 += __shfl_down(p2, o, 64);
            p3 += __shfl_down(p3, o, 64);
        }
        if (lane == 0) {
            s1023r[wv][0] = p0; s1023r[wv][1] = p1;
            s1023r[wv][2] = p2; s1023r[wv][3] = p3;
        }
    }
    __syncthreads();
    if (t == 0) {
        s1023.x = s1023r[0][0] + s1023r[1][0];
        s1023.y = s1023r[0][1] + s1023r[1][1];
        s1023.z = s1023r[0][2] + s1023r[1][2];
        s1023.w = s1023r[0][3] + s1023r[1][3];
    }
    __syncthreads();

    // ---- main GEMM stream: acc[m] = s[4t-1..4t+2, u0+m] ----
    float4 acc0 = {0,0,0,0}, acc1 = {0,0,0,0}, acc2 = {0,0,0,0}, acc3 = {0,0,0,0};
    const float4* sp = (const float4*)state + t;
    #pragma unroll 8
    for (int k = 0; k < U; ++k) {
        const float4 f  = sp[k * (W / 4)];      // state[k, 4t..4t+3], coalesced
        const float4 vk = v4[k];                // LDS broadcast
        acc0.x = fmaf(vk.x, f.x, acc0.x); acc0.y = fmaf(vk.x, f.y, acc0.y);
        acc0.z = fmaf(vk.x, f.z, acc0.z); acc0.w = fmaf(vk.x, f.w, acc0.w);
        acc1.x = fmaf(vk.y, f.x, acc1.x); acc1.y = fmaf(vk.y, f.y, acc1.y);
        acc1.z = fmaf(vk.y, f.z, acc1.z); acc1.w = fmaf(vk.y, f.w, acc1.w);
        acc2.x = fmaf(vk.z, f.x, acc2.x); acc2.y = fmaf(vk.z, f.y, acc2.y);
        acc2.z = fmaf(vk.z, f.z, acc2.z); acc2.w = fmaf(vk.z, f.w, acc2.w);
        acc3.x = fmaf(vk.w, f.x, acc3.x); acc3.y = fmaf(vk.w, f.y, acc3.y);
        acc3.z = fmaf(vk.w, f.z, acc3.z); acc3.w = fmaf(vk.w, f.w, acc3.w);
    }
    // patch thread 0's dead j=-1 slot with j=1023
    if (t == 0) {
        acc0.x = s1023.x; acc1.x = s1023.y; acc2.x = s1023.z; acc3.x = s1023.w;
    }

    // ---- numerator weights fs[j, u0+m] = state[u0+m, 4t..4t+3] ----
    float4 g0 = *((const float4*)(state + (size_t)(u0 + 0) * W) + t);
    float4 g1 = *((const float4*)(state + (size_t)(u0 + 1) * W) + t);
    float4 g2 = *((const float4*)(state + (size_t)(u0 + 2) * W) + t);
    float4 g3 = *((const float4*)(state + (size_t)(u0 + 3) * W) + t);
    if (t == 0) {
        g0.x = input[u0 + 0]; g1.x = input[u0 + 1];
        g2.x = input[u0 + 2]; g3.x = input[u0 + 3];
    }

    // ---- softmax partials (no max subtraction needed, |s| <~ 8) ----
    float num0, num1, num2, num3, den0, den1, den2, den3;
    {
        float4 e;
        e.x = __expf(acc0.x); e.y = __expf(acc0.y); e.z = __expf(acc0.z); e.w = __expf(acc0.w);
        den0 = e.x + e.y + e.z + e.w;
        num0 = fmaf(g0.x, e.x, fmaf(g0.y, e.y, fmaf(g0.z, e.z, g0.w * e.w)));
        e.x = __expf(acc1.x); e.y = __expf(acc1.y); e.z = __expf(acc1.z); e.w = __expf(acc1.w);
        den1 = e.x + e.y + e.z + e.w;
        num1 = fmaf(g1.x, e.x, fmaf(g1.y, e.y, fmaf(g1.z, e.z, g1.w * e.w)));
        e.x = __expf(acc2.x); e.y = __expf(acc2.y); e.z = __expf(acc2.z); e.w = __expf(acc2.w);
        den2 = e.x + e.y + e.z + e.w;
        num2 = fmaf(g2.x, e.x, fmaf(g2.y, e.y, fmaf(g2.z, e.z, g2.w * e.w)));
        e.x = __expf(acc3.x); e.y = __expf(acc3.y); e.z = __expf(acc3.z); e.w = __expf(acc3.w);
        den3 = e.x + e.y + e.z + e.w;
        num3 = fmaf(g3.x, e.x, fmaf(g3.y, e.y, fmaf(g3.z, e.z, g3.w * e.w)));
    }
    #pragma unroll
    for (int o = 32; o > 0; o >>= 1) {
        num0 += __shfl_down(num0, o, 64); num1 += __shfl_down(num1, o, 64);
        num2 += __shfl_down(num2, o, 64); num3 += __shfl_down(num3, o, 64);
        den0 += __shfl_down(den0, o, 64); den1 += __shfl_down(den1, o, 64);
        den2 += __shfl_down(den2, o, 64); den3 += __shfl_down(den3, o, 64);
    }
    if (lane == 0) {
        red[wv][0] = num0; red[wv][1] = num1; red[wv][2] = num2; red[wv][3] = num3;
        red[wv][4] = den0; red[wv][5] = den1; red[wv][6] = den2; red[wv][7] = den3;
    }
    __syncthreads();

    if (t < 8)  fin[t] = red[0][t] + red[1][t] + red[2][t] + red[3][t];
    __syncthreads();
    if (t < 4)  out[u0 + t] = fin[t] / fin[t + 4];
}

extern "C" void kernel_launch(void* const* d_in, const int* in_sizes, int n_in,
                              void* d_out, int out_size, void* d_ws, size_t ws_size,
                              hipStream_t stream) {
    const float* input = (const float*)d_in[0];   // (1,128)
    const float* state = (const float*)d_in[1];   // (128,1024)
    const float* w     = (const float*)d_in[2];   // (257,128)
    // d_in[3] = b (zeros; cancels in softmax) -- unused
    float* out = (float*)d_out;                   // (1,128)

    rsa_last_kernel<<<dim3(U / 4), dim3(256), 0, stream>>>(input, state, w, out);
}

// Round 5
// 62.683 us; speedup vs baseline: 1.4088x; 1.4088x over previous
//
#include <hip/hip_runtime.h>

// RSA layer, last-row-only, 2-D tiled (j x u) formulation.
//
// out[u] = (sum_j e^{s[j,u]} * fs[j,u]) / (sum_j e^{s[j,u]})
//   s[j,u] = sum_k fs[j,k] * v[k,u],   v[k,u] = w_hi[k,u] + w_dot[u]*input[k]
// (proj_hj[1023,:] and b are constant in j -> cancel in the softmax over j;
//  |s| <~ 8 so e^s is fp32-safe without max subtraction -> partials over j
//  are linearly mergeable across blocks.)
// fs[j,k] = state[k, j+1] for j<1023;  fs[1023,k] = input[k].
//
// Grid: 256 blocks = 64 j-tiles (16 j each) x 4 u-quarters (32 u each).
// Block (jt,uq) reads ONLY: w_hi[:, 32uq:32uq+32] (16 KB), state cols
// [16jt,16jt+16) (8 KB), input, w_dot quarter -> ~7 float4 loads per thread,
// all independent, ONE cold-latency round. Column c maps to j=c-1; block 0's
// dead c=0 slot is patched with j=1023 (fs=input). Partial num/den per u go
// to ws; a tiny second kernel reduces 64 j-tiles and divides.

constexpr int U    = 128;
constexpr int W    = 1024;
constexpr int JT   = 16;    // j's per block
constexpr int SSTR = 132;   // sliceT row stride floats; 132%32==4, 16B-aligned

__global__ __launch_bounds__(256) void rsa_part(
    const float* __restrict__ input,   // (128,)
    const float* __restrict__ state,   // (128,1024) row-major
    const float* __restrict__ w,       // (257,128) row-major
    float* __restrict__ ws)            // (4,64,64): [uq][jt][num32|den32]
{
    const int bid = blockIdx.x;
    const int jt  = bid >> 2;          // 0..63
    const int uq  = bid & 3;           // 0..3
    const int t   = threadIdx.x;
    const int uu  = t & 7;             // float4 u-group within the 32-u slice
    const int j   = (t >> 3) & 15;     // j_local
    const int kh  = t >> 7;            // k-half

    __shared__ __align__(16) float sliceT[JT][SSTR]; // fs[j_local][k]
    __shared__ __align__(16) float vv[U][32];        // v[k][u_local]
    __shared__ __align__(16) float sin_[U];
    __shared__ __align__(16) float mrg[JT][8][4];    // kh=1 partial acc
    __shared__ __align__(16) float red2[2][8][8];    // per-wave j-reduced {num4,den4}

    // ---- issue ALL global loads up front (one vmcnt round) ----
    float4 in4;
    if (t < 32) in4 = ((const float4*)input)[t];
    const float4 wdq = ((const float4*)(w + 2 * U * U + uq * 32))[uu];
    float4 wh[4];
    #pragma unroll
    for (int i = 0; i < 4; ++i) {
        const int k = (t >> 3) + 32 * i;
        wh[i] = ((const float4*)w)[k * 32 + uq * 8 + uu];     // w_hi[k, u-slice]
    }
    float4 st[2];
    #pragma unroll
    for (int i = 0; i < 2; ++i) {
        const int p = t + 256 * i;                            // 0..511
        const int k = p >> 2;
        const int j4 = p & 3;
        st[i] = ((const float4*)state)[k * 256 + jt * 4 + j4]; // cols 16jt+4j4..+3
    }

    if (t < 32) ((float4*)sin_)[t] = in4;
    __syncthreads();                                          // sin_ ready

    // ---- build vv[k][u] = w_hi + w_dot*input[k]; stage sliceT (transpose) ----
    #pragma unroll
    for (int i = 0; i < 4; ++i) {
        const int k = (t >> 3) + 32 * i;
        const float ik = sin_[k];
        float4 r;
        r.x = fmaf(wdq.x, ik, wh[i].x);
        r.y = fmaf(wdq.y, ik, wh[i].y);
        r.z = fmaf(wdq.z, ik, wh[i].z);
        r.w = fmaf(wdq.w, ik, wh[i].w);
        *(float4*)&vv[k][4 * uu] = r;
    }
    #pragma unroll
    for (int i = 0; i < 2; ++i) {
        const int p = t + 256 * i;
        const int k = p >> 2;
        const int j4 = p & 3;
        sliceT[4 * j4 + 0][k] = st[i].x;
        sliceT[4 * j4 + 1][k] = st[i].y;
        sliceT[4 * j4 + 2][k] = st[i].z;
        sliceT[4 * j4 + 3][k] = st[i].w;
    }
    __syncthreads();                                          // staged
    if (jt == 0 && t < U) sliceT[0][t] = sin_[t];             // c=0 -> j=1023
    __syncthreads();

    // ---- GEMM: acc[m] = partial_k s[j, uq*32+4uu+m] over k-half ----
    const int kb0 = kh * 64;
    const float* aR = &sliceT[j][kb0];
    float4 acc = {0.f, 0.f, 0.f, 0.f};
    #pragma unroll
    for (int kc = 0; kc < 16; ++kc) {
        const float4 a4 = *(const float4*)(aR + 4 * kc);
        const float4 v0 = *(const float4*)&vv[kb0 + 4 * kc + 0][4 * uu];
        const float4 v1 = *(const float4*)&vv[kb0 + 4 * kc + 1][4 * uu];
        const float4 v2 = *(const float4*)&vv[kb0 + 4 * kc + 2][4 * uu];
        const float4 v3 = *(const float4*)&vv[kb0 + 4 * kc + 3][4 * uu];
        acc.x = fmaf(a4.x, v0.x, acc.x); acc.y = fmaf(a4.x, v0.y, acc.y);
        acc.z = fmaf(a4.x, v0.z, acc.z); acc.w = fmaf(a4.x, v0.w, acc.w);
        acc.x = fmaf(a4.y, v1.x, acc.x); acc.y = fmaf(a4.y, v1.y, acc.y);
        acc.z = fmaf(a4.y, v1.z, acc.z); acc.w = fmaf(a4.y, v1.w, acc.w);
        acc.x = fmaf(a4.z, v2.x, acc.x); acc.y = fmaf(a4.z, v2.y, acc.y);
        acc.z = fmaf(a4.z, v2.z, acc.z); acc.w = fmaf(a4.z, v2.w, acc.w);
        acc.x = fmaf(a4.w, v3.x, acc.x); acc.y = fmaf(a4.w, v3.y, acc.y);
        acc.z = fmaf(a4.w, v3.z, acc.z); acc.w = fmaf(a4.w, v3.w, acc.w);
    }

    // ---- merge k-halves ----
    if (kh) *(float4*)&mrg[j][uu][0] = acc;
    __syncthreads();
    if (!kh) {
        const float4 o = *(const float4*)&mrg[j][uu][0];
        acc.x += o.x; acc.y += o.y; acc.z += o.z; acc.w += o.w;

        // softmax partials for this (j, u0..u0+3)
        const float4 fs4 = *(const float4*)&sliceT[j][uq * 32 + 4 * uu];
        float4 e, n;
        e.x = __expf(acc.x); e.y = __expf(acc.y);
        e.z = __expf(acc.z); e.w = __expf(acc.w);
        n.x = fs4.x * e.x;   n.y = fs4.y * e.y;
        n.z = fs4.z * e.z;   n.w = fs4.w * e.w;

        // reduce over the wave's 8 j's (lanes strided by 8 share uu)
        #pragma unroll
        for (int o8 = 8; o8 < 64; o8 <<= 1) {
            n.x += __shfl_down(n.x, o8, 64); n.y += __shfl_down(n.y, o8, 64);
            n.z += __shfl_down(n.z, o8, 64); n.w += __shfl_down(n.w, o8, 64);
            e.x += __shfl_down(e.x, o8, 64); e.y += __shfl_down(e.y, o8, 64);
            e.z += __shfl_down(e.z, o8, 64); e.w += __shfl_down(e.w, o8, 64);
        }
        const int lane = t & 63, wv = t >> 6;                 // wv in {0,1}
        if (lane < 8) {
            red2[wv][lane][0] = n.x; red2[wv][lane][1] = n.y;
            red2[wv][lane][2] = n.z; red2[wv][lane][3] = n.w;
            red2[wv][lane][4] = e.x; red2[wv][lane][5] = e.y;
            red2[wv][lane][6] = e.z; red2[wv][lane][7] = e.w;
        }
    }
    __syncthreads();

    if (t < 32) {
        const int ug = t >> 2, m = t & 3;
        const float num = red2[0][ug][m]     + red2[1][ug][m];
        const float den = red2[0][ug][4 + m] + red2[1][ug][4 + m];
        const int base = (uq * 64 + jt) * 64;
        ws[base + t]      = num;
        ws[base + 32 + t] = den;
    }
}

__global__ __launch_bounds__(256) void rsa_fin(
    const float* __restrict__ ws, float* __restrict__ out)
{
    __shared__ float sden[U];
    const int t  = threadIdx.x;
    const int u  = t & (U - 1);
    const int nd = t >> 7;                     // 0: num, 1: den
    const float* base = ws + (size_t)(u >> 5) * 64 * 64 + nd * 32 + (u & 31);
    float s = 0.0f;
    #pragma unroll 16
    for (int jt = 0; jt < 64; ++jt) s += base[jt * 64];
    if (nd) sden[u] = s;
    __syncthreads();
    if (!nd) out[u] = s / sden[u];
}

extern "C" void kernel_launch(void* const* d_in, const int* in_sizes, int n_in,
                              void* d_out, int out_size, void* d_ws, size_t ws_size,
                              hipStream_t stream) {
    const float* input = (const float*)d_in[0];   // (1,128)
    const float* state = (const float*)d_in[1];   // (128,1024)
    const float* w     = (const float*)d_in[2];   // (257,128)
    // d_in[3] = b (zeros; cancels in softmax) -- unused
    float* out = (float*)d_out;                   // (1,128)
    float* ws  = (float*)d_ws;                    // 64 KB partials

    rsa_part<<<dim3(256), dim3(256), 0, stream>>>(input, state, w, ws);
    rsa_fin<<<dim3(1), dim3(256), 0, stream>>>(ws, out);
}